// Round 2
// baseline (375.122 us; speedup 1.0000x reference)
//
#include <hip/hip_runtime.h>
#include <stdint.h>

#define SEQN 16384
#define NBATCH 4

typedef __attribute__((ext_vector_type(8))) __bf16 bf16x8;
typedef __attribute__((ext_vector_type(4))) float f32x4;
typedef __attribute__((ext_vector_type(4))) unsigned int u32x4;

__device__ __forceinline__ unsigned int f2bf(float f) {
  unsigned int x = __builtin_bit_cast(unsigned int, f);
  x = x + 0x7fffu + ((x >> 16) & 1u);
  return x >> 16;
}
__device__ __forceinline__ float bf2f(unsigned int lo) {
  return __builtin_bit_cast(float, lo << 16);
}

__device__ __forceinline__ void gload_lds16(const unsigned short* g, unsigned char* l) {
  __builtin_amdgcn_global_load_lds(
      (const __attribute__((address_space(1))) unsigned int*)g,
      (__attribute__((address_space(3))) unsigned int*)l, 16, 0, 0);
}

// C = A @ Bt^T + bias.  A: [M][512] bf16 row-major, Bt: [Ncols][512] bf16 row-major.
// 256x256 tile, BK=32, 8 waves (2Mx4N), 4-buffer LDS ring (128 KiB), depth-3
// prefetch with counted vmcnt(12) (T3/T4), setprio around MFMA cluster (T5),
// conflict-free LDS granule layout via pre-permuted global source (rule #21),
// XCD-aware block swizzle (T1).
template<bool OUT_BF16>
__global__ __launch_bounds__(512, 1)
void gemm256(const unsigned short* __restrict__ A,
             const unsigned short* __restrict__ Bt,
             const float* __restrict__ bias,
             void* __restrict__ Cout,
             int Ncols)
{
  extern __shared__ __align__(16) unsigned char smem[];  // 4 * (16KiB A + 16KiB B)
  const int K = 512;
  const int tid = threadIdx.x;
  const int lane = tid & 63;
  const int wid = tid >> 6;
  const int wr = (wid >> 2) << 7;   // 0 or 128
  const int wc = (wid & 3) << 6;    // 0,64,128,192
  const int nbx = Ncols >> 8;
  const int nwg = (int)gridDim.x;
  const int bid = (int)blockIdx.x;
  const int cpx = nwg >> 3;
  const int swz = (bid & 7) * cpx + (bid >> 3);   // XCD swizzle (nwg%8==0)
  const int bx = swz % nbx;
  const int by = swz / nbx;
  const long row0 = (long)by << 8;
  const int col0 = bx << 8;

  // stage source element-offsets (granule G = i*512+tid holds LDS bytes G*16..+16;
  // LDS layout: granule index = r*4 + (c ^ ((r>>1)&3)), r=tile row, c=16B k-chunk)
  int srcA[2], srcB[2];
#pragma unroll
  for (int i = 0; i < 2; ++i) {
    const int G = i * 512 + tid;
    const int r = G >> 2;
    const int c = (G & 3) ^ ((G >> 3) & 3);
    srcA[i] = (int)(row0 + r) * K + c * 8;
    srcB[i] = (col0 + r) * K + c * 8;
  }

  // frag ds_read byte offsets (within matrix region of a buffer)
  int aoff[8], boff[4];
#pragma unroll
  for (int fm = 0; fm < 8; ++fm) {
    const int r = wr + fm * 16 + (lane & 15);
    aoff[fm] = r * 64 + ((((lane >> 4)) ^ ((r >> 1) & 3)) << 4);
  }
#pragma unroll
  for (int fn = 0; fn < 4; ++fn) {
    const int r = wc + fn * 16 + (lane & 15);
    boff[fn] = r * 64 + ((((lane >> 4)) ^ ((r >> 1) & 3)) << 4);
  }

  f32x4 acc[8][4];
#pragma unroll
  for (int i = 0; i < 8; ++i)
#pragma unroll
    for (int j = 0; j < 4; ++j) acc[i][j] = (f32x4)0.0f;

#define STAGE(t)                                                            \
  {                                                                         \
    unsigned char* buf_ = smem + ((t) & 3) * 32768;                         \
    const int kt_ = (t) * 32;                                               \
    gload_lds16(A + srcA[0] + kt_, buf_ + tid * 16);                        \
    gload_lds16(Bt + srcB[0] + kt_, buf_ + 16384 + tid * 16);               \
    gload_lds16(A + srcA[1] + kt_, buf_ + 8192 + tid * 16);                 \
    gload_lds16(Bt + srcB[1] + kt_, buf_ + 24576 + tid * 16);               \
  }

#define COMPUTE(t)                                                          \
  {                                                                         \
    const unsigned char* buf_ = smem + ((t) & 3) * 32768;                   \
    bf16x8 af[8], bfv[4];                                                   \
    _Pragma("unroll")                                                       \
    for (int fm = 0; fm < 8; ++fm)                                          \
      af[fm] = __builtin_bit_cast(bf16x8, *(const u32x4*)(buf_ + aoff[fm]));\
    _Pragma("unroll")                                                       \
    for (int fn = 0; fn < 4; ++fn)                                          \
      bfv[fn] = __builtin_bit_cast(bf16x8,                                  \
                    *(const u32x4*)(buf_ + 16384 + boff[fn]));              \
    __builtin_amdgcn_s_setprio(1);                                          \
    _Pragma("unroll")                                                       \
    for (int fm = 0; fm < 8; ++fm)                                          \
      _Pragma("unroll")                                                     \
      for (int fn = 0; fn < 4; ++fn)                                        \
        acc[fm][fn] = __builtin_amdgcn_mfma_f32_16x16x32_bf16(              \
            af[fm], bfv[fn], acc[fm][fn], 0, 0, 0);                         \
    __builtin_amdgcn_s_setprio(0);                                          \
  }

  STAGE(0); STAGE(1); STAGE(2);
  for (int t = 0; t < 13; ++t) {
    STAGE(t + 3);
    asm volatile("s_waitcnt vmcnt(12)" ::: "memory");
    __syncthreads();
    COMPUTE(t);
    __syncthreads();
  }
  asm volatile("s_waitcnt vmcnt(8)" ::: "memory");
  __syncthreads(); COMPUTE(13); __syncthreads();
  asm volatile("s_waitcnt vmcnt(4)" ::: "memory");
  __syncthreads(); COMPUTE(14); __syncthreads();
  asm volatile("s_waitcnt vmcnt(0)" ::: "memory");
  __syncthreads(); COMPUTE(15);
#undef STAGE
#undef COMPUTE

#pragma unroll
  for (int fn = 0; fn < 4; ++fn) {
    const int n = col0 + wc + fn * 16 + (lane & 15);
    const float bn = bias[n];
#pragma unroll
    for (int fm = 0; fm < 8; ++fm) {
      const long mbase = row0 + wr + fm * 16 + ((lane >> 4) << 2);
#pragma unroll
      for (int j = 0; j < 4; ++j) {
        const float v = acc[fm][fn][j] + bn;
        if constexpr (OUT_BF16)
          ((unsigned short*)Cout)[(mbase + j) * (long)Ncols + n] = (unsigned short)f2bf(v);
        else
          ((float*)Cout)[(mbase + j) * (long)Ncols + n] = v;
      }
    }
  }
}

// One wave per (b,n) row. qkv row layout: [q(512) | k(512) | v(512)] bf16.
__global__ __launch_bounds__(256)
void nbr_attn(const unsigned short* __restrict__ qkv,
              const int* __restrict__ nbr,
              unsigned short* __restrict__ aout)
{
  const int wid = (int)((blockIdx.x * 256 + threadIdx.x) >> 6);
  const int lane = threadIdx.x & 63;
  const int n = wid & (SEQN - 1);
  const int b = wid >> 14;

  const unsigned short* qrow = qkv + (size_t)wid * 1536;
  float qv[8];
  {
    const u32x4 raw = *(const u32x4*)(qrow + lane * 8);
#pragma unroll
    for (int i = 0; i < 4; ++i) {
      qv[2 * i] = bf2f(raw[i] & 0xffffu);
      qv[2 * i + 1] = bf2f(raw[i] >> 16);
    }
  }
  float s[3];
  u32x4 vraw[3];
  bool val[3];
#pragma unroll
  for (int k = 0; k < 3; ++k) {
    const int t = nbr[k * SEQN + n];
    val[k] = (t != -1);
    const int j = t > 0 ? t : 0;
    const unsigned short* krow = qkv + ((size_t)(b * SEQN + j)) * 1536 + 512;
    const u32x4 kraw = *(const u32x4*)(krow + lane * 8);
    vraw[k] = *(const u32x4*)(krow + 512 + lane * 8);
    float d = 0.f;
#pragma unroll
    for (int i = 0; i < 4; ++i)
      d += qv[2 * i] * bf2f(kraw[i] & 0xffffu) + qv[2 * i + 1] * bf2f(kraw[i] >> 16);
    d += __shfl_xor(d, 1);
    d += __shfl_xor(d, 2);
    d += __shfl_xor(d, 4);
    s[k] = d * 0.125f;
  }
  float m = -3.0e38f;
#pragma unroll
  for (int k = 0; k < 3; ++k)
    if (val[k]) m = fmaxf(m, s[k]);
  float e[3], sum = 0.f;
#pragma unroll
  for (int k = 0; k < 3; ++k) {
    e[k] = val[k] ? __expf(s[k] - m) : 0.f;
    sum += e[k];
  }
  const float inv = sum > 0.f ? 1.f / sum : 0.f;
  float acc[8] = {0.f, 0.f, 0.f, 0.f, 0.f, 0.f, 0.f, 0.f};
#pragma unroll
  for (int k = 0; k < 3; ++k) {
    const float w = e[k] * inv;
#pragma unroll
    for (int i = 0; i < 4; ++i) {
      acc[2 * i] += w * bf2f(vraw[k][i] & 0xffffu);
      acc[2 * i + 1] += w * bf2f(vraw[k][i] >> 16);
    }
  }
  u32x4 o;
#pragma unroll
  for (int i = 0; i < 4; ++i)
    o[i] = f2bf(acc[2 * i]) | (f2bf(acc[2 * i + 1]) << 16);
  *(u32x4*)(aout + (size_t)wid * 512 + lane * 8) = o;
}

__global__ __launch_bounds__(256)
void cvt_f32_bf16(const float* __restrict__ in, unsigned short* __restrict__ out, int n8) {
  int i = blockIdx.x * 256 + threadIdx.x;
  const int stride = gridDim.x * 256;
  for (; i < n8; i += stride) {
    const float4* p = (const float4*)(in + (size_t)i * 8);
    const float4 a = p[0], c = p[1];
    u32x4 o;
    o[0] = f2bf(a.x) | (f2bf(a.y) << 16);
    o[1] = f2bf(a.z) | (f2bf(a.w) << 16);
    o[2] = f2bf(c.x) | (f2bf(c.y) << 16);
    o[3] = f2bf(c.z) | (f2bf(c.w) << 16);
    *(u32x4*)(out + (size_t)i * 8) = o;
  }
}

__global__ __launch_bounds__(256)
void prep_w(const float* __restrict__ Wq, const float* __restrict__ Wk,
            const float* __restrict__ Wv, const float* __restrict__ Wo,
            const float* __restrict__ bq, const float* __restrict__ bk,
            const float* __restrict__ bv,
            unsigned short* __restrict__ wf, unsigned short* __restrict__ wo,
            float* __restrict__ biasf)
{
  const int i = blockIdx.x * 256 + threadIdx.x;
  const int stride = gridDim.x * 256;
  for (int t = i; t < 262144; t += stride) {
    wf[t] = (unsigned short)f2bf(Wq[t]);
    wf[262144 + t] = (unsigned short)f2bf(Wk[t]);
    wf[524288 + t] = (unsigned short)f2bf(Wv[t]);
    wo[t] = (unsigned short)f2bf(Wo[t]);
  }
  if (i < 512) {
    biasf[i] = bq[i];
    biasf[512 + i] = bk[i];
    biasf[1024 + i] = bv[i];
  }
}

extern "C" void kernel_launch(void* const* d_in, const int* in_sizes, int n_in,
                              void* d_out, int out_size, void* d_ws, size_t ws_size,
                              hipStream_t stream) {
  const float* x  = (const float*)d_in[0];
  const int* nbr  = (const int*)d_in[1];
  const float* Wq = (const float*)d_in[2];
  const float* bq = (const float*)d_in[3];
  const float* Wk = (const float*)d_in[4];
  const float* bk = (const float*)d_in[5];
  const float* Wv = (const float*)d_in[6];
  const float* bv = (const float*)d_in[7];
  const float* Wo = (const float*)d_in[8];
  const float* bo = (const float*)d_in[9];
  float* out = (float*)d_out;
  unsigned char* ws = (unsigned char*)d_ws;

  unsigned short* xb  = (unsigned short*)(ws);
  unsigned short* qkv = (unsigned short*)(ws + 67108864UL);
  unsigned short* wf  = (unsigned short*)(ws + 268435456UL);
  unsigned short* wo  = (unsigned short*)(ws + 270008320UL);
  float* biasf        = (float*)(ws + 270532608UL);

  static bool attr_done = false;
  if (!attr_done) {
    hipFuncSetAttribute((const void*)gemm256<true>,
                        hipFuncAttributeMaxDynamicSharedMemorySize, 131072);
    hipFuncSetAttribute((const void*)gemm256<false>,
                        hipFuncAttributeMaxDynamicSharedMemorySize, 131072);
    attr_done = true;
  }

  cvt_f32_bf16<<<4096, 256, 0, stream>>>(x, xb, 33554432 / 8);
  prep_w<<<1024, 256, 0, stream>>>(Wq, Wk, Wv, Wo, bq, bk, bv, wf, wo, biasf);
  // QKV projection: M=65536, N=1536, K=512 -> grid 256*6
  gemm256<true><<<dim3(256 * 6), 512, 131072, stream>>>(xb, wf, biasf, qkv, 1536);
  // neighbor attention (reuses xb region for output; x_bf16 is dead)
  nbr_attn<<<16384, 256, 0, stream>>>(qkv, nbr, xb);
  // output projection: M=65536, N=512, K=512 -> grid 256*2
  gemm256<false><<<dim3(256 * 2), 512, 131072, stream>>>(xb, wo, bo, out, 512);
}

// Round 4
// 284.339 us; speedup vs baseline: 1.3193x; 1.3193x over previous
//
#include <hip/hip_runtime.h>
#include <stdint.h>

#define SEQN 16384
#define NBATCH 4

typedef __attribute__((ext_vector_type(8))) __bf16 bf16x8;
typedef __attribute__((ext_vector_type(4))) float f32x4;
typedef __attribute__((ext_vector_type(4))) unsigned int u32x4;

__device__ __forceinline__ unsigned int f2bf(float f) {
  unsigned int x = __builtin_bit_cast(unsigned int, f);
  x = x + 0x7fffu + ((x >> 16) & 1u);
  return x >> 16;
}
__device__ __forceinline__ float bf2f(unsigned int lo) {
  return __builtin_bit_cast(float, lo << 16);
}

__device__ __forceinline__ void gload_lds16(const unsigned short* g, unsigned char* l) {
  __builtin_amdgcn_global_load_lds(
      (const __attribute__((address_space(1))) unsigned int*)g,
      (__attribute__((address_space(3))) unsigned int*)l, 16, 0, 0);
}

// C = A @ Bt^T + bias.  A: [M][K] bf16 row-major, Bt: [Ncols][K] bf16 row-major.
// m97-style 128x128 tile, BK=64, 4 waves (2x2), proven-safe 2-barrier loop
// (__syncthreads drain semantics). LDS XOR-swizzle via pre-swizzled global
// source (rule #21). T1 XCD-chunked block swizzle: consecutive same-row blocks
// colocate on one XCD so the A-panel stays L2-resident (R1 FETCH=267MB showed
// A-panel rereads going to HBM).
template<bool OUT_BF16>
__global__ __launch_bounds__(256, 4)
void gemm_bt(const unsigned short* __restrict__ A,
             const unsigned short* __restrict__ Bt,
             const float* __restrict__ bias,
             void* __restrict__ Cout,
             int Ncols, int K)
{
  __shared__ __align__(16) unsigned char lA[128 * 64 * 2];
  __shared__ __align__(16) unsigned char lB[128 * 64 * 2];
  const int tid = threadIdx.x;
  const int lane = tid & 63;
  const int wid = tid >> 6;
  const int wr = (wid >> 1) * 64;   // wave row offset in tile
  const int wc = (wid & 1) * 64;    // wave col offset in tile
  const int nbx = Ncols >> 7;
  // T1: XCD-chunked swizzle (gridDim.x % 8 == 0 -> bijective)
  const int bid = (int)blockIdx.x;
  const int cpx = (int)gridDim.x >> 3;
  const int swz = (bid & 7) * cpx + (bid >> 3);
  const int bx = swz % nbx;
  const int by = swz / nbx;
  const long row0 = (long)by << 7;
  const int col0 = bx << 7;

  f32x4 acc[4][4];
#pragma unroll
  for (int i = 0; i < 4; ++i)
#pragma unroll
    for (int j = 0; j < 4; ++j) acc[i][j] = (f32x4)0.0f;

  for (int kt = 0; kt < K; kt += 64) {
#pragma unroll
    for (int i = 0; i < 4; ++i) {
      const int f = i * 256 + tid;          // 16B chunk index 0..1023
      const int r = f >> 3;                 // tile row 0..127
      const int cd = (f & 7) ^ (r & 7);     // inverse-swizzled source chunk
      gload_lds16(A + (row0 + r) * (long)K + kt + cd * 8, lA + f * 16);
      gload_lds16(Bt + (long)(col0 + r) * K + kt + cd * 8, lB + f * 16);
    }
    __syncthreads();
#pragma unroll
    for (int kk = 0; kk < 2; ++kk) {
      bf16x8 af[4], bfv[4];
#pragma unroll
      for (int fm = 0; fm < 4; ++fm) {
        const int row = wr + fm * 16 + (lane & 15);
        const int ch = (kk * 4 + (lane >> 4)) ^ (row & 7);
        af[fm] = __builtin_bit_cast(bf16x8, *(const u32x4*)(lA + row * 128 + ch * 16));
      }
#pragma unroll
      for (int fn = 0; fn < 4; ++fn) {
        const int row = wc + fn * 16 + (lane & 15);
        const int ch = (kk * 4 + (lane >> 4)) ^ (row & 7);
        bfv[fn] = __builtin_bit_cast(bf16x8, *(const u32x4*)(lB + row * 128 + ch * 16));
      }
#pragma unroll
      for (int fm = 0; fm < 4; ++fm)
#pragma unroll
        for (int fn = 0; fn < 4; ++fn)
          acc[fm][fn] = __builtin_amdgcn_mfma_f32_16x16x32_bf16(af[fm], bfv[fn], acc[fm][fn], 0, 0, 0);
    }
    __syncthreads();
  }

#pragma unroll
  for (int fn = 0; fn < 4; ++fn) {
    const int n = col0 + wc + fn * 16 + (lane & 15);
    const float bn = bias[n];
#pragma unroll
    for (int fm = 0; fm < 4; ++fm) {
      const long mbase = row0 + wr + fm * 16 + ((lane >> 4) << 2);
#pragma unroll
      for (int j = 0; j < 4; ++j) {
        const float v = acc[fm][fn][j] + bn;
        if constexpr (OUT_BF16)
          ((unsigned short*)Cout)[(mbase + j) * (long)Ncols + n] = (unsigned short)f2bf(v);
        else
          ((float*)Cout)[(mbase + j) * (long)Ncols + n] = v;
      }
    }
  }
}

// One wave per (b,n) row. qkv row layout: [q(512) | k(512) | v(512)] bf16.
// lane l covers dims [l*8, l*8+8) == head h=l>>3, d-segment (l&7)*8.
// All 6 gather loads (3x K-row, 3x V-row) issued before the reduce chains.
__global__ __launch_bounds__(256)
void nbr_attn(const unsigned short* __restrict__ qkv,
              const int* __restrict__ nbr,
              unsigned short* __restrict__ aout)
{
  const int wid = (int)((blockIdx.x * 256 + threadIdx.x) >> 6);
  const int lane = threadIdx.x & 63;
  const int n = wid & (SEQN - 1);
  const int b = wid >> 14;

  const unsigned short* qrow = qkv + (size_t)wid * 1536;
  const u32x4 qraw = *(const u32x4*)(qrow + lane * 8);

  int t0 = nbr[n];
  int t1 = nbr[SEQN + n];
  int t2 = nbr[2 * SEQN + n];
  bool val[3] = {t0 != -1, t1 != -1, t2 != -1};
  const unsigned short* base = qkv + (size_t)b * SEQN * 1536 + 512 + lane * 8;
  const unsigned short* k0 = base + (size_t)(t0 > 0 ? t0 : 0) * 1536;
  const unsigned short* k1 = base + (size_t)(t1 > 0 ? t1 : 0) * 1536;
  const unsigned short* k2 = base + (size_t)(t2 > 0 ? t2 : 0) * 1536;
  u32x4 kraw[3], vraw[3];
  kraw[0] = *(const u32x4*)k0;
  vraw[0] = *(const u32x4*)(k0 + 512);
  kraw[1] = *(const u32x4*)k1;
  vraw[1] = *(const u32x4*)(k1 + 512);
  kraw[2] = *(const u32x4*)k2;
  vraw[2] = *(const u32x4*)(k2 + 512);

  float qv[8];
#pragma unroll
  for (int i = 0; i < 4; ++i) {
    qv[2 * i] = bf2f(qraw[i] & 0xffffu);
    qv[2 * i + 1] = bf2f(qraw[i] >> 16);
  }
  float s[3];
#pragma unroll
  for (int k = 0; k < 3; ++k) {
    float d = 0.f;
#pragma unroll
    for (int i = 0; i < 4; ++i)
      d += qv[2 * i] * bf2f(kraw[k][i] & 0xffffu) + qv[2 * i + 1] * bf2f(kraw[k][i] >> 16);
    d += __shfl_xor(d, 1);
    d += __shfl_xor(d, 2);
    d += __shfl_xor(d, 4);
    s[k] = d * 0.125f;
  }
  float m = -3.0e38f;
#pragma unroll
  for (int k = 0; k < 3; ++k)
    if (val[k]) m = fmaxf(m, s[k]);
  float e[3], sum = 0.f;
#pragma unroll
  for (int k = 0; k < 3; ++k) {
    e[k] = val[k] ? __expf(s[k] - m) : 0.f;
    sum += e[k];
  }
  const float inv = sum > 0.f ? 1.f / sum : 0.f;
  float acc[8] = {0.f, 0.f, 0.f, 0.f, 0.f, 0.f, 0.f, 0.f};
#pragma unroll
  for (int k = 0; k < 3; ++k) {
    const float w = e[k] * inv;
#pragma unroll
    for (int i = 0; i < 4; ++i) {
      acc[2 * i] += w * bf2f(vraw[k][i] & 0xffffu);
      acc[2 * i + 1] += w * bf2f(vraw[k][i] >> 16);
    }
  }
  u32x4 o;
#pragma unroll
  for (int i = 0; i < 4; ++i)
    o[i] = f2bf(acc[2 * i]) | (f2bf(acc[2 * i + 1]) << 16);
  *(u32x4*)(aout + (size_t)wid * 512 + lane * 8) = o;
}

__global__ __launch_bounds__(256)
void cvt_f32_bf16(const float* __restrict__ in, unsigned short* __restrict__ out, int n8) {
  int i = blockIdx.x * 256 + threadIdx.x;
  const int stride = gridDim.x * 256;
  for (; i < n8; i += stride) {
    const float4* p = (const float4*)(in + (size_t)i * 8);
    const float4 a = p[0], c = p[1];
    u32x4 o;
    o[0] = f2bf(a.x) | (f2bf(a.y) << 16);
    o[1] = f2bf(a.z) | (f2bf(a.w) << 16);
    o[2] = f2bf(c.x) | (f2bf(c.y) << 16);
    o[3] = f2bf(c.z) | (f2bf(c.w) << 16);
    *(u32x4*)(out + (size_t)i * 8) = o;
  }
}

__global__ __launch_bounds__(256)
void prep_w(const float* __restrict__ Wq, const float* __restrict__ Wk,
            const float* __restrict__ Wv, const float* __restrict__ Wo,
            const float* __restrict__ bq, const float* __restrict__ bk,
            const float* __restrict__ bv,
            unsigned short* __restrict__ wf, unsigned short* __restrict__ wo,
            float* __restrict__ biasf)
{
  const int i = blockIdx.x * 256 + threadIdx.x;
  const int stride = gridDim.x * 256;
  for (int t = i; t < 262144; t += stride) {
    wf[t] = (unsigned short)f2bf(Wq[t]);
    wf[262144 + t] = (unsigned short)f2bf(Wk[t]);
    wf[524288 + t] = (unsigned short)f2bf(Wv[t]);
    wo[t] = (unsigned short)f2bf(Wo[t]);
  }
  if (i < 512) {
    biasf[i] = bq[i];
    biasf[512 + i] = bk[i];
    biasf[1024 + i] = bv[i];
  }
}

extern "C" void kernel_launch(void* const* d_in, const int* in_sizes, int n_in,
                              void* d_out, int out_size, void* d_ws, size_t ws_size,
                              hipStream_t stream) {
  const float* x  = (const float*)d_in[0];
  const int* nbr  = (const int*)d_in[1];
  const float* Wq = (const float*)d_in[2];
  const float* bq = (const float*)d_in[3];
  const float* Wk = (const float*)d_in[4];
  const float* bk = (const float*)d_in[5];
  const float* Wv = (const float*)d_in[6];
  const float* bv = (const float*)d_in[7];
  const float* Wo = (const float*)d_in[8];
  const float* bo = (const float*)d_in[9];
  float* out = (float*)d_out;
  unsigned char* ws = (unsigned char*)d_ws;

  // ws layout (bytes):
  //   [0, 64Mi)            x_bf16, later reused as attn_out_bf16 (65536*512*2)
  //   [64Mi, 256Mi)        qkv bf16 (65536*1536*2 = 192Mi)
  //   [256Mi, +1.5Mi)      fused W (Wq;Wk;Wv) bf16 [1536][512]
  //   [..., +0.5Mi)        Wo bf16 [512][512]
  //   [..., +6Ki)          fused bias f32 [1536]
  unsigned short* xb  = (unsigned short*)(ws);
  unsigned short* qkv = (unsigned short*)(ws + 67108864UL);
  unsigned short* wf  = (unsigned short*)(ws + 268435456UL);
  unsigned short* wo  = (unsigned short*)(ws + 270008320UL);
  float* biasf        = (float*)(ws + 270532608UL);

  cvt_f32_bf16<<<4096, 256, 0, stream>>>(x, xb, 33554432 / 8);
  prep_w<<<1024, 256, 0, stream>>>(Wq, Wk, Wv, Wo, bq, bk, bv, wf, wo, biasf);
  // QKV projection: M=65536, N=1536, K=512
  gemm_bt<true><<<dim3(512 * 12), 256, 0, stream>>>(xb, wf, biasf, qkv, 1536, 512);
  // neighbor attention (reuses xb region for output; x_bf16 is dead)
  nbr_attn<<<16384, 256, 0, stream>>>(qkv, nbr, xb);
  // output projection: M=65536, N=512, K=512, f32 out
  gemm_bt<false><<<dim3(512 * 4), 256, 0, stream>>>(xb, wo, bo, out, 512, 512);
}